// Round 1
// baseline (351.769 us; speedup 1.0000x reference)
//
#include <hip/hip_runtime.h>
#include <math.h>

// Problem constants (from reference): N=256, C=4, F=256, NB=32, OC*OF=1024
namespace {
constexpr int N_ = 256, C_ = 4, F_ = 256, NB_ = 32;
constexpr int K_ = 2048;            // 2*C*F contraction length
constexpr int O_ = 1024;            // OC*OF
constexpr int OUT_ELEMS = N_ * O_;  // 262144 floats, then adj follows in d_out
}

// One block per (n,c) pair. Key algebra: fadj[a,b] = x[a]*s[b] + x[b]*s[a]
// (rank-1 + transpose, s = sum over 32 neighbors), t = signsqrt(fadj) is
// SYMMETRIC, adj[a,b] = t[a,b] * inv[b], inv[b] = 1/(sum_a |t[a,b]| + 1e-7).
// ax[b] = sum_a adj[b,a] x[a] = sum_a t[a,b] * (inv[a]*x[a])  (symmetry!)
// => thread b owns column b: coalesced adj stores + register ax accumulation.
__global__ __launch_bounds__(256) void adj_kernel(
    const float* __restrict__ x,         // (N,C,F)
    const float* __restrict__ neighbor,  // (N,NB,C,F)
    float* __restrict__ adj,             // (N,C,F,F) -> d_out + OUT_ELEMS
    float* __restrict__ ax_out)          // (N,C,F) workspace
{
  __shared__ float x_l[F_], s_l[F_], w_l[F_];
  const int blk = blockIdx.x;
  const int n = blk >> 2, c = blk & 3;
  const int b = threadIdx.x;

  // Stage x row and neighbor-sum row into LDS (coalesced reads).
  const float xb = x[(n * C_ + c) * F_ + b];
  x_l[b] = xb;
  const float* nb_ptr = neighbor + ((size_t)(n * NB_) * C_ + c) * F_ + b;
  float sb = 0.f;
  #pragma unroll
  for (int j = 0; j < NB_; ++j) sb += nb_ptr[(size_t)j * C_ * F_];
  s_l[b] = sb;
  __syncthreads();

  // Phase 1: column sum of |t| for column b.
  float colsum = 0.f;
  #pragma unroll 8
  for (int a = 0; a < F_; ++a) {
    float v = fmaf(x_l[a], sb, xb * s_l[a]);
    float r = __builtin_amdgcn_sqrtf(fmaxf(fabsf(v), 1e-8f));
    colsum += (v != 0.f) ? r : 0.f;  // sign(0)*sqrt(...) == 0 in reference
  }
  const float inv = 1.f / (colsum + 1e-7f);
  w_l[b] = inv * xb;  // broadcast weights for ax accumulation
  __syncthreads();

  // Phase 2: recompute t, write adj column (coalesced over b), accumulate ax[b].
  float axb = 0.f;
  float* adj_col = adj + (size_t)(n * C_ + c) * F_ * F_ + b;
  #pragma unroll 4
  for (int a = 0; a < F_; ++a) {
    float v = fmaf(x_l[a], sb, xb * s_l[a]);
    float r = __builtin_amdgcn_sqrtf(fmaxf(fabsf(v), 1e-8f));
    float t = (v != 0.f) ? copysignf(r, v) : 0.f;
    adj_col[(size_t)a * F_] = t * inv;
    axb = fmaf(t, w_l[a], axb);
  }
  ax_out[(n * C_ + c) * F_ + b] = axb;
}

// out[n][o] = sum_k xcat[n][k] * W[o][k], xcat = [ax | x] split at k=1024.
// 32x32 output tile per 64-thread (1-wave) block, 4x4 register tile per lane,
// BK=32 LDS staging, split-K=8 via fp32 atomics (out pre-zeroed).
__global__ __launch_bounds__(64) void gemm_kernel(
    const float* __restrict__ ax,  // (256,1024)
    const float* __restrict__ x,   // (256,1024)
    const float* __restrict__ W,   // (1024,2048)
    float* __restrict__ out)       // (256,1024)
{
  __shared__ float As[32][36];  // +4 pad: float4-aligned, breaks pow2 strides
  __shared__ float Bs[32][36];
  const int m0 = blockIdx.x * 32;   // n tile (8)
  const int o0 = blockIdx.y * 32;   // o tile (32)
  const int kb = blockIdx.z;        // split-K chunk (8), 256 K each
  const int lane = threadIdx.x;
  const int lx = lane & 7, ly = lane >> 3;

  float acc[4][4] = {};
  const int kbeg = kb * 256;
  for (int k0 = kbeg; k0 < kbeg + 256; k0 += 32) {
    // Each 256-wide K chunk lies entirely in the ax half or the x half.
    const float* Abase = (k0 < 1024) ? (ax + k0) : (x + (k0 - 1024));
    #pragma unroll
    for (int i = 0; i < 16; ++i) {
      int idx = i * 64 + lane;
      int r = idx >> 5, kk = idx & 31;  // consecutive lanes -> consecutive kk
      As[r][kk] = Abase[(size_t)(m0 + r) * 1024 + kk];
      Bs[r][kk] = W[(size_t)(o0 + r) * 2048 + k0 + kk];
    }
    __syncthreads();
    #pragma unroll
    for (int kk = 0; kk < 32; ++kk) {
      float a4[4], b4[4];
      #pragma unroll
      for (int i = 0; i < 4; ++i) a4[i] = As[ly * 4 + i][kk];
      #pragma unroll
      for (int j = 0; j < 4; ++j) b4[j] = Bs[lx * 4 + j][kk];
      #pragma unroll
      for (int i = 0; i < 4; ++i)
        #pragma unroll
        for (int j = 0; j < 4; ++j)
          acc[i][j] = fmaf(a4[i], b4[j], acc[i][j]);
    }
    __syncthreads();
  }
  #pragma unroll
  for (int i = 0; i < 4; ++i)
    #pragma unroll
    for (int j = 0; j < 4; ++j)
      atomicAdd(&out[(size_t)(m0 + ly * 4 + i) * 1024 + o0 + lx * 4 + j],
                acc[i][j]);
}

extern "C" void kernel_launch(void* const* d_in, const int* in_sizes, int n_in,
                              void* d_out, int out_size, void* d_ws,
                              size_t ws_size, hipStream_t stream) {
  const float* x = (const float*)d_in[0];         // (256,4,256)
  const float* neighbor = (const float*)d_in[1];  // (256,32,4,256)
  const float* W = (const float*)d_in[2];         // (1024,8,256)
  float* out = (float*)d_out;                     // output 0: (256,4,256)
  float* adj = out + OUT_ELEMS;                   // output 1: (256,4,256,256)
  float* ax = (float*)d_ws;                       // 1 MB scratch

  // Zero the atomic split-K target (d_ws/d_out are poisoned 0xAA each call).
  hipMemsetAsync(out, 0, OUT_ELEMS * sizeof(float), stream);

  adj_kernel<<<dim3(N_ * C_), dim3(256), 0, stream>>>(x, neighbor, adj, ax);
  gemm_kernel<<<dim3(N_ / 32, O_ / 32, 8), dim3(64), 0, stream>>>(ax, x, W,
                                                                  out);
}

// Round 3
// 344.956 us; speedup vs baseline: 1.0198x; 1.0198x over previous
//
#include <hip/hip_runtime.h>
#include <math.h>

// Problem constants: N=256, C=4, F=256, NB=32, OC*OF=1024, K=2048
namespace {
constexpr int N_ = 256, C_ = 4, F_ = 256, NB_ = 32;
constexpr int O_ = 1024;
constexpr int OUT_ELEMS = N_ * O_;  // out (256,1024), then adj follows
typedef float f32x4 __attribute__((ext_vector_type(4)));  // native vec for nontemporal
}

// One block per (n,c). Algebra: fadj[a,b] = x[a]*s[b] + x[b]*s[a] (rank-1 sym,
// s = neighbor-sum), t = signsqrt(fadj) symmetric, adj[a,b] = t[a,b]*inv[b],
// inv[b] = 1/(colsum_a |t[a,b]| + 1e-7), ax[b] = sum_a t[a,b]*(inv[a]*x[a]).
// Thread t: row-slice rs = t>>6 (64 rows), columns b0..b0+3 (b0 = (t&63)*4)
// held in registers -> float4 nontemporal adj stores, 2 LDS broadcasts per
// 4 elements (vs 3 per element before).
__global__ __launch_bounds__(256) void adj_kernel(
    const float* __restrict__ x,         // (N,C,F)
    const float* __restrict__ neighbor,  // (N,NB,C,F)
    float* __restrict__ adj,             // (N,C,F,F)
    float* __restrict__ ax_out)          // (N,C,F) workspace
{
  __shared__ float x_l[F_], s_l[F_], w_l[F_];
  __shared__ float red[4][F_];
  const int blk = blockIdx.x;
  const int n = blk >> 2, c = blk & 3;
  const int t = threadIdx.x;
  const int rs = t >> 6;         // row slice (wave id), rows [rs*64, rs*64+64)
  const int lane = t & 63;
  const int b0 = lane * 4;       // 4 owned columns

  // Stage x row and neighbor-sum row (coalesced).
  const int base = (n * C_ + c) * F_;
  x_l[t] = x[base + t];
  {
    const float* p = neighbor + ((size_t)(n * NB_) * C_ + c) * F_ + t;
    float s = 0.f;
    #pragma unroll
    for (int j = 0; j < NB_; ++j) s += p[(size_t)j * C_ * F_];
    s_l[t] = s;
  }
  __syncthreads();

  const float4 xb4 = *(const float4*)&x_l[b0];
  const float4 sb4 = *(const float4*)&s_l[b0];
  const float xbv[4] = {xb4.x, xb4.y, xb4.z, xb4.w};
  const float sbv[4] = {sb4.x, sb4.y, sb4.z, sb4.w};

  // Phase 1: partial column sums of |t| over this thread's 64 rows.
  float cs[4] = {0.f, 0.f, 0.f, 0.f};
  const int a0r = rs * 64;
  #pragma unroll 4
  for (int a = a0r; a < a0r + 64; ++a) {
    const float xa = x_l[a], sa = s_l[a];
    #pragma unroll
    for (int j = 0; j < 4; ++j) {
      float v = fmaf(xa, sbv[j], xbv[j] * sa);
      float r = __builtin_amdgcn_sqrtf(fmaxf(fabsf(v), 1e-8f));
      cs[j] += (v != 0.f) ? r : 0.f;  // sign(0)*sqrt == 0 in reference
    }
  }
  *(float4*)&red[rs][b0] = make_float4(cs[0], cs[1], cs[2], cs[3]);
  __syncthreads();

  float invv[4];
  {
    const float4 r0 = *(const float4*)&red[0][b0];
    const float4 r1 = *(const float4*)&red[1][b0];
    const float4 r2 = *(const float4*)&red[2][b0];
    const float4 r3 = *(const float4*)&red[3][b0];
    invv[0] = 1.f / (r0.x + r1.x + r2.x + r3.x + 1e-7f);
    invv[1] = 1.f / (r0.y + r1.y + r2.y + r3.y + 1e-7f);
    invv[2] = 1.f / (r0.z + r1.z + r2.z + r3.z + 1e-7f);
    invv[3] = 1.f / (r0.w + r1.w + r2.w + r3.w + 1e-7f);
  }
  if (rs == 0) {
    *(float4*)&w_l[b0] = make_float4(invv[0] * xbv[0], invv[1] * xbv[1],
                                     invv[2] * xbv[2], invv[3] * xbv[3]);
  }
  __syncthreads();

  // Phase 2: recompute t, float4 nontemporal adj stores, ax accumulation.
  float axp[4] = {0.f, 0.f, 0.f, 0.f};
  float* arow = adj + (size_t)(n * C_ + c) * (F_ * F_);
  #pragma unroll 2
  for (int a = a0r; a < a0r + 64; ++a) {
    const float xa = x_l[a], sa = s_l[a], wa = w_l[a];
    float o[4];
    #pragma unroll
    for (int j = 0; j < 4; ++j) {
      float v = fmaf(xa, sbv[j], xbv[j] * sa);
      float r = __builtin_amdgcn_sqrtf(fmaxf(fabsf(v), 1e-8f));
      float tt = (v != 0.f) ? copysignf(r, v) : 0.f;
      o[j] = tt * invv[j];
      axp[j] = fmaf(tt, wa, axp[j]);
    }
    f32x4 ov = {o[0], o[1], o[2], o[3]};
    __builtin_nontemporal_store(ov, (f32x4*)&arow[(size_t)a * F_ + b0]);
  }
  *(float4*)&red[rs][b0] = make_float4(axp[0], axp[1], axp[2], axp[3]);
  __syncthreads();
  if (rs == 0) {
    const float4 r0 = *(const float4*)&red[0][b0];
    const float4 r1 = *(const float4*)&red[1][b0];
    const float4 r2 = *(const float4*)&red[2][b0];
    const float4 r3 = *(const float4*)&red[3][b0];
    const float4 axv = make_float4(r0.x + r1.x + r2.x + r3.x,
                                   r0.y + r1.y + r2.y + r3.y,
                                   r0.z + r1.z + r2.z + r3.z,
                                   r0.w + r1.w + r2.w + r3.w);
    *(float4*)&ax_out[base + b0] = axv;
  }
}

// out[m][o] = sum_k xcat[m][k] W[o][k], xcat = [ax | x] split at k=1024.
// 64x64 tile, 256 threads (4 waves), 4x4 register tile/thread, BK=32 staged
// TRANSPOSED in LDS so inner loop = 2 ds_read_b128 + 16 fma per kk.
// split-K=8 via fp32 atomics (out pre-zeroed).
__global__ __launch_bounds__(256) void gemm_kernel(
    const float* __restrict__ ax,  // (256,1024)
    const float* __restrict__ x,   // (256,1024)
    const float* __restrict__ W,   // (1024,2048)
    float* __restrict__ out)       // (256,1024)
{
  __shared__ float As[32][64];  // [kk][m]
  __shared__ float Bs[32][64];  // [kk][o]
  const int tid = threadIdx.x;
  const int m0 = blockIdx.x * 64, o0 = blockIdx.y * 64;
  const int mi = tid >> 4, oi = tid & 15;       // 4x4 tile at (mi*4, oi*4)
  const int r = tid >> 2, kq = (tid & 3) * 8;   // staging: row r, 8 k's
  float acc[4][4] = {};

  const int kbeg = blockIdx.z * 256;
  for (int k0 = kbeg; k0 < kbeg + 256; k0 += 32) {
    // 256-aligned K chunks lie entirely in the ax half or the x half.
    const float* Ab = (k0 < 1024) ? ax + k0 : x + (k0 - 1024);
    const float4 a0 = *(const float4*)&Ab[(size_t)(m0 + r) * 1024 + kq];
    const float4 a1 = *(const float4*)&Ab[(size_t)(m0 + r) * 1024 + kq + 4];
    const float4 b0 = *(const float4*)&W[(size_t)(o0 + r) * 2048 + k0 + kq];
    const float4 b1 = *(const float4*)&W[(size_t)(o0 + r) * 2048 + k0 + kq + 4];
    __syncthreads();  // previous tile's reads complete
    As[kq + 0][r] = a0.x; As[kq + 1][r] = a0.y;
    As[kq + 2][r] = a0.z; As[kq + 3][r] = a0.w;
    As[kq + 4][r] = a1.x; As[kq + 5][r] = a1.y;
    As[kq + 6][r] = a1.z; As[kq + 7][r] = a1.w;
    Bs[kq + 0][r] = b0.x; Bs[kq + 1][r] = b0.y;
    Bs[kq + 2][r] = b0.z; Bs[kq + 3][r] = b0.w;
    Bs[kq + 4][r] = b1.x; Bs[kq + 5][r] = b1.y;
    Bs[kq + 6][r] = b1.z; Bs[kq + 7][r] = b1.w;
    __syncthreads();
    #pragma unroll
    for (int kk = 0; kk < 32; ++kk) {
      const float4 av = *(const float4*)&As[kk][mi * 4];
      const float4 bv = *(const float4*)&Bs[kk][oi * 4];
      const float am[4] = {av.x, av.y, av.z, av.w};
      const float bm[4] = {bv.x, bv.y, bv.z, bv.w};
      #pragma unroll
      for (int i = 0; i < 4; ++i)
        #pragma unroll
        for (int j = 0; j < 4; ++j)
          acc[i][j] = fmaf(am[i], bm[j], acc[i][j]);
    }
  }
  #pragma unroll
  for (int i = 0; i < 4; ++i)
    #pragma unroll
    for (int j = 0; j < 4; ++j)
      atomicAdd(&out[(size_t)(m0 + mi * 4 + i) * 1024 + o0 + oi * 4 + j],
                acc[i][j]);
}

extern "C" void kernel_launch(void* const* d_in, const int* in_sizes, int n_in,
                              void* d_out, int out_size, void* d_ws,
                              size_t ws_size, hipStream_t stream) {
  const float* x = (const float*)d_in[0];         // (256,4,256)
  const float* neighbor = (const float*)d_in[1];  // (256,32,4,256)
  const float* W = (const float*)d_in[2];         // (1024,2048)
  float* out = (float*)d_out;                     // output 0: (256,1024)
  float* adj = out + OUT_ELEMS;                   // output 1: (256,4,256,256)
  float* ax = (float*)d_ws;                       // 1 MB scratch

  (void)hipMemsetAsync(out, 0, OUT_ELEMS * sizeof(float), stream);
  adj_kernel<<<dim3(N_ * C_), dim3(256), 0, stream>>>(x, neighbor, adj, ax);
  gemm_kernel<<<dim3(256 / 64, O_ / 64, 8), dim3(256), 0, stream>>>(ax, x, W,
                                                                    out);
}